// Round 1
// baseline (1884.624 us; speedup 1.0000x reference)
//
#include <hip/hip_runtime.h>
#include <math.h>

#define DEPTH 17
#define NNODES ((1 << DEPTH) - 1)

typedef _Float16 f16x8 __attribute__((ext_vector_type(8)));
typedef float f32x4 __attribute__((ext_vector_type(4)));

__device__ __forceinline__ float sigmoid_(float v) {
  return 1.0f / (1.0f + __expf(-v));
}
__device__ __forceinline__ float tanh_(float v) {
  float t = __expf(-2.0f * fabsf(v));
  float r = (1.0f - t) / (1.0f + t);
  return v < 0.0f ? -r : r;
}

// Pack combined weight matrix Wb[1280][768] f16, K contiguous per row:
//  rows 0..767   : [ W_iou (256) | U_iou (512) ]   -> iou outputs
//  rows 768..1279: [ 0     (256) | U_f_w (512) ]   -> f-gate outputs
__global__ __launch_bounds__(256) void build_wb(
    _Float16* __restrict__ Wb, const float* __restrict__ W_iou,
    const float* __restrict__ U_iou, const float* __restrict__ U_f_w) {
  int idx = blockIdx.x * 256 + threadIdx.x;  // grid covers exactly 1280*768
  int rw = idx / 768, k = idx - rw * 768;
  float v;
  if (rw < 768) {
    v = (k < 256) ? W_iou[rw * 256 + k] : U_iou[rw * 512 + (k - 256)];
  } else {
    v = (k < 256) ? 0.0f : U_f_w[(rw - 768) * 512 + (k - 256)];
  }
  Wb[idx] = (_Float16)v;
}

// One level: fused GEMM (A[m,K] @ Wb^T) + TreeLSTM node apply.
// Block: 16 rows x 1280 cols (LEAF: 768 cols). 4 waves; wave w owns
// n in [64w, 64w+64) for ALL gate groups -> epilogue is wave-local.
template <bool LEAF, typename CT>
__global__ __launch_bounds__(256) void level_kernel(
    const float* __restrict__ x, const float* __restrict__ c0in,
    const _Float16* __restrict__ Wb, const float* __restrict__ b_iou,
    const float* __restrict__ U_f_b, float* __restrict__ out,
    CT* __restrict__ cws, int m, int off, int coff) {
  constexpr int KC = LEAF ? 32 : 96;      // 8-elem chunks per A row
  constexpr int KSTEPS = LEAF ? 8 : 24;   // K / 32
  constexpr int NG = LEAF ? 3 : 5;        // gate groups of 256 cols
  __shared__ f16x8 sA[16 * KC];           // 16 rows x K f16, XOR-swizzled

  const int tid = threadIdx.x;
  const int pbase = blockIdx.x << 4;

  // ---- stage A: f32 (x | h_children) -> f16 LDS, swizzle ^(row&7) on 16B units
#pragma unroll
  for (int it = 0; it < (16 * KC) / 256; ++it) {
    int cid = tid + it * 256;
    int row = cid / KC;
    int kc = cid - row * KC;
    int p = pbase + row;
    f16x8 v = {};
    if (p < m) {
      const float* src;
      if (LEAF || kc < 32)
        src = x + (size_t)(off + p) * 256 + kc * 8;
      else
        src = out + (size_t)(coff + 2 * p) * 256 + (size_t)(kc - 32) * 8;
      float4 f0 = *(const float4*)(src);
      float4 f1 = *(const float4*)(src + 4);
      v[0] = (_Float16)f0.x; v[1] = (_Float16)f0.y;
      v[2] = (_Float16)f0.z; v[3] = (_Float16)f0.w;
      v[4] = (_Float16)f1.x; v[5] = (_Float16)f1.y;
      v[6] = (_Float16)f1.z; v[7] = (_Float16)f1.w;
    }
    sA[(row * KC + kc) ^ (row & 7)] = v;
  }
  __syncthreads();

  const int lane = tid & 63;
  const int w = tid >> 6;
  const int l15 = lane & 15;
  const int q = lane >> 4;

  f32x4 acc[NG][4] = {};

  // B: lane reads Wb[col][k..k+7], col = g*256 + w*64 + t*16 + l15
  const _Float16* wbase = Wb + (size_t)(w * 64 + l15) * 768 + q * 8;

  for (int ks = 0; ks < KSTEPS; ++ks) {
    f16x8 a = sA[(l15 * KC + ks * 4 + q) ^ (l15 & 7)];
#pragma unroll
    for (int g = 0; g < NG; ++g) {
#pragma unroll
      for (int t = 0; t < 4; ++t) {
        f16x8 b = *(const f16x8*)(wbase + (size_t)(g * 256 + t * 16) * 768 + ks * 32);
        acc[g][t] = __builtin_amdgcn_mfma_f32_16x16x32_f16(a, b, acc[g][t], 0, 0, 0);
      }
    }
  }

  // ---- epilogue: gates in f32, write h (d_out) and c (ws)
  const int n0 = (w << 6) + l15;
  const int rb = q << 2;
#pragma unroll
  for (int t = 0; t < 4; ++t) {
    const int n = n0 + t * 16;
    const float bi = b_iou[n];
    const float bo = b_iou[256 + n];
    const float bu = b_iou[512 + n];
    float bf0 = 0.f, bf1 = 0.f;
    if (!LEAF) { bf0 = U_f_b[n]; bf1 = U_f_b[256 + n]; }
#pragma unroll
    for (int r = 0; r < 4; ++r) {
      const int p = pbase + rb + r;
      if (p < m) {
        const float iv = sigmoid_(acc[0][t][r] + bi);
        const float ov = sigmoid_(acc[1][t][r] + bo);
        const float uv = tanh_(acc[2][t][r] + bu);
        float cred;
        if (LEAF) {
          cred = c0in[(size_t)(off + p) * 256 + n];
        } else {
          const size_t cb = (size_t)(coff + 2 * p) * 256 + n;
          const float f0 = sigmoid_(acc[3][t][r] + bf0);
          const float f1 = sigmoid_(acc[4][t][r] + bf1);
          cred = f0 * (float)cws[cb] + f1 * (float)cws[cb + 256];
        }
        const float c = iv * uv + cred;
        const float h = ov * tanh_(c);
        const size_t ob = (size_t)(off + p) * 256 + n;
        out[ob] = h;
        cws[ob] = (CT)c;
      }
    }
  }
}

template <typename CT>
static void run_levels(const float* x, const float* c0, const _Float16* Wb,
                       const float* b_iou, const float* U_f_b, float* out,
                       CT* cws, hipStream_t stream) {
  // leaves: level 16, m = 65536, off = 65535
  level_kernel<true, CT><<<4096, 256, 0, stream>>>(x, c0, Wb, b_iou, U_f_b,
                                                   out, cws, 65536, 65535, 0);
  for (int k = DEPTH - 2; k >= 0; --k) {
    const int m = 1 << k;
    level_kernel<false, CT><<<dim3((m + 15) / 16), 256, 0, stream>>>(
        x, c0, Wb, b_iou, U_f_b, out, cws, m, m - 1, 2 * m - 1);
  }
}

extern "C" void kernel_launch(void* const* d_in, const int* in_sizes, int n_in,
                              void* d_out, int out_size, void* d_ws, size_t ws_size,
                              hipStream_t stream) {
  const float* x     = (const float*)d_in[0];
  // d_in[1] = h0 (unused by the reference's math)
  const float* c0    = (const float*)d_in[2];
  const float* W_iou = (const float*)d_in[3];
  const float* U_iou = (const float*)d_in[4];
  const float* b_iou = (const float*)d_in[5];
  const float* U_f_w = (const float*)d_in[6];
  const float* U_f_b = (const float*)d_in[7];
  float* out = (float*)d_out;

  char* ws = (char*)d_ws;
  const size_t wbBytes = (size_t)1280 * 768 * 2;  // 1.97 MB, 256B-aligned
  _Float16* Wb = (_Float16*)ws;
  build_wb<<<3840, 256, 0, stream>>>(Wb, W_iou, U_iou, U_f_w);

  const size_t cElems = (size_t)NNODES * 256;
  if (ws_size >= wbBytes + cElems * 4) {
    run_levels<float>(x, c0, Wb, b_iou, U_f_b, out,
                      (float*)(ws + wbBytes), stream);
  } else {
    // fallback: f16 cell state if the workspace is small
    run_levels<_Float16>(x, c0, Wb, b_iou, U_f_b, out,
                         (_Float16*)(ws + wbBytes), stream);
  }
}

// Round 2
// 713.092 us; speedup vs baseline: 2.6429x; 2.6429x over previous
//
#include <hip/hip_runtime.h>
#include <math.h>

#define DEPTH 17
#define NNODES ((1 << DEPTH) - 1)

typedef _Float16 f16x8 __attribute__((ext_vector_type(8)));
typedef float f32x4 __attribute__((ext_vector_type(4)));

__device__ __forceinline__ float sigmoid_(float v) {
  return 1.0f / (1.0f + __expf(-v));
}
__device__ __forceinline__ float tanh_(float v) {
  float t = __expf(-2.0f * fabsf(v));
  float r = (1.0f - t) / (1.0f + t);
  return v < 0.0f ? -r : r;
}

// Pack combined weight matrix Wb[1280][768] f16, K contiguous per row:
//  rows 0..767   : [ W_iou (256) | U_iou (512) ]   -> iou outputs
//  rows 768..1279: [ 0     (256) | U_f_w (512) ]   -> f-gate outputs
__global__ __launch_bounds__(256) void build_wb(
    _Float16* __restrict__ Wb, const float* __restrict__ W_iou,
    const float* __restrict__ U_iou, const float* __restrict__ U_f_w) {
  int idx = blockIdx.x * 256 + threadIdx.x;  // grid covers exactly 1280*768
  int rw = idx / 768, k = idx - rw * 768;
  float v;
  if (rw < 768) {
    v = (k < 256) ? W_iou[rw * 256 + k] : U_iou[rw * 512 + (k - 256)];
  } else {
    v = (k < 256) ? 0.0f : U_f_w[(rw - 768) * 512 + (k - 256)];
  }
  Wb[idx] = (_Float16)v;
}

// One level: fused GEMM (A[m, K] @ Wb^T) + TreeLSTM node apply.
// Block tile: 64 rows x 64 n-values (x NG gate groups). 4 waves; wave w owns
// all 64 rows for n in [nb*64 + w*16, +16) across ALL groups -> wave-local
// epilogue. B staged to LDS via global_load_lds (linear dest, pre-swizzled
// source); A reg-staged f32->f16 with the same XOR swizzle; reads use
// swizzled ds_read_b128 (rule 21: both-sides-or-neither).
template <bool LEAF, typename CT>
__global__ __launch_bounds__(256) void level_kernel(
    const float* __restrict__ x, const float* __restrict__ c0in,
    const _Float16* __restrict__ Wb, const float* __restrict__ b_iou,
    const float* __restrict__ U_f_b, float* __restrict__ out,
    CT* __restrict__ cws, int m, int off, int coff) {
  constexpr int NG = LEAF ? 3 : 5;       // gate groups (cols = NG*64 per block)
  constexpr int NCH = LEAF ? 4 : 12;     // K / 64
  constexpr int BROWS = NG * 64;         // B-tile rows (= output cols staged)
  constexpr int NBU = BROWS * 8 / 256;   // gload_lds units per thread (6 / 10)
  __shared__ f16x8 sA[64 * 8];           // 64 rows x 64 k f16 (8 KB)
  __shared__ f16x8 sB[BROWS * 8];        // BROWS x 64 k f16 (24 / 40 KB)

  const int tid = threadIdx.x;
  const int w = tid >> 6;
  const int lane = tid & 63;
  const int l15 = lane & 15;
  const int q = lane >> 4;
  const int pbase = blockIdx.x << 6;
  const int nb = blockIdx.y;             // n-split index, 0..3

  f32x4 acc[NG][4] = {};

  for (int c = 0; c < NCH; ++c) {
    // ---- stage A: 2 units/thread, reg-staged f32 -> f16, swizzled slot
    f16x8 av[2];
#pragma unroll
    for (int j = 0; j < 2; ++j) {
      const int s = tid + j * 256;       // linear LDS unit index
      const int row = s >> 3;
      const int sw = s & 7;
      const int p = pbase + row;
      // logical unit stored in this swizzled slot:
      const int k0 = (c << 6) + ((sw ^ (row & 7)) << 3);
      f16x8 v = {};
      if (p < m) {
        const float* src;
        if (LEAF || k0 < 256)
          src = x + (size_t)(off + p) * 256 + k0;
        else
          src = out + (size_t)(coff + 2 * p) * 256 + (k0 - 256);
        float4 f0 = *(const float4*)src;
        float4 f1 = *(const float4*)(src + 4);
        v[0] = (_Float16)f0.x; v[1] = (_Float16)f0.y;
        v[2] = (_Float16)f0.z; v[3] = (_Float16)f0.w;
        v[4] = (_Float16)f1.x; v[5] = (_Float16)f1.y;
        v[6] = (_Float16)f1.z; v[7] = (_Float16)f1.w;
      }
      av[j] = v;
    }
    // ---- stage B: coalesced global_load_lds, linear dest + pre-swz source
#pragma unroll
    for (int j = 0; j < NBU; ++j) {
      const int s = tid + j * 256;
      const int r = s >> 3;              // B-tile row (output col index)
      const int sw = s & 7;
      const int g = r >> 6;
      const int i = r & 63;
      const int wbrow = g * 256 + nb * 64 + i;
      const _Float16* src =
          Wb + (size_t)wbrow * 768 + (c << 6) + ((sw ^ (r & 7)) << 3);
      __builtin_amdgcn_global_load_lds(
          (const __attribute__((address_space(1))) void*)src,
          (__attribute__((address_space(3))) void*)&sB[s], 16, 0, 0);
    }
    sA[tid] = av[0];
    sA[tid + 256] = av[1];
    __syncthreads();

    // ---- compute: 2 k-slices x NG groups x 4 row-frags MFMA
#pragma unroll
    for (int ks = 0; ks < 2; ++ks) {
      f16x8 af[4];
#pragma unroll
      for (int rf = 0; rf < 4; ++rf) {
        const int row = rf * 16 + l15;
        af[rf] = sA[(row << 3) | ((ks * 4 + q) ^ (row & 7))];
      }
#pragma unroll
      for (int g = 0; g < NG; ++g) {
        const int r = g * 64 + w * 16 + l15;
        const f16x8 bf = sB[(r << 3) | ((ks * 4 + q) ^ (r & 7))];
#pragma unroll
        for (int rf = 0; rf < 4; ++rf)
          acc[g][rf] = __builtin_amdgcn_mfma_f32_16x16x32_f16(
              af[rf], bf, acc[g][rf], 0, 0, 0);
      }
    }
    __syncthreads();
  }

  // ---- epilogue: gates in f32, write h (d_out) and c (ws)
  const int n = nb * 64 + w * 16 + l15;  // n-value in [0,256)
  const float bi = b_iou[n];
  const float bo = b_iou[256 + n];
  const float bu = b_iou[512 + n];
  float bf0 = 0.f, bf1 = 0.f;
  if (!LEAF) { bf0 = U_f_b[n]; bf1 = U_f_b[256 + n]; }
#pragma unroll
  for (int rf = 0; rf < 4; ++rf) {
#pragma unroll
    for (int r = 0; r < 4; ++r) {
      const int p = pbase + rf * 16 + (q << 2) + r;
      if (p < m) {
        const float iv = sigmoid_(acc[0][rf][r] + bi);
        const float ov = sigmoid_(acc[1][rf][r] + bo);
        const float uv = tanh_(acc[2][rf][r] + bu);
        float cred;
        if (LEAF) {
          cred = c0in[(size_t)(off + p) * 256 + n];
        } else {
          const size_t cb = (size_t)(coff + 2 * p) * 256 + n;
          const float f0 = sigmoid_(acc[3][rf][r] + bf0);
          const float f1 = sigmoid_(acc[4][rf][r] + bf1);
          cred = f0 * (float)cws[cb] + f1 * (float)cws[cb + 256];
        }
        const float cc = iv * uv + cred;
        const float hh = ov * tanh_(cc);
        const size_t ob = (size_t)(off + p) * 256 + n;
        out[ob] = hh;
        cws[ob] = (CT)cc;
      }
    }
  }
}

template <typename CT>
static void run_levels(const float* x, const float* c0, const _Float16* Wb,
                       const float* b_iou, const float* U_f_b, float* out,
                       CT* cws, hipStream_t stream) {
  // leaves: level 16, m = 65536, off = 65535
  level_kernel<true, CT><<<dim3(1024, 4), 256, 0, stream>>>(
      x, c0, Wb, b_iou, U_f_b, out, cws, 65536, 65535, 0);
  for (int k = DEPTH - 2; k >= 0; --k) {
    const int m = 1 << k;
    level_kernel<false, CT><<<dim3((m + 63) / 64, 4), 256, 0, stream>>>(
        x, c0, Wb, b_iou, U_f_b, out, cws, m, m - 1, 2 * m - 1);
  }
}

extern "C" void kernel_launch(void* const* d_in, const int* in_sizes, int n_in,
                              void* d_out, int out_size, void* d_ws, size_t ws_size,
                              hipStream_t stream) {
  const float* x     = (const float*)d_in[0];
  // d_in[1] = h0 (unused by the reference's math)
  const float* c0    = (const float*)d_in[2];
  const float* W_iou = (const float*)d_in[3];
  const float* U_iou = (const float*)d_in[4];
  const float* b_iou = (const float*)d_in[5];
  const float* U_f_w = (const float*)d_in[6];
  const float* U_f_b = (const float*)d_in[7];
  float* out = (float*)d_out;

  char* ws = (char*)d_ws;
  const size_t wbBytes = (size_t)1280 * 768 * 2;  // 1.97 MB, 256B-aligned
  _Float16* Wb = (_Float16*)ws;
  build_wb<<<3840, 256, 0, stream>>>(Wb, W_iou, U_iou, U_f_w);

  const size_t cElems = (size_t)NNODES * 256;
  if (ws_size >= wbBytes + cElems * 4) {
    run_levels<float>(x, c0, Wb, b_iou, U_f_b, out,
                      (float*)(ws + wbBytes), stream);
  } else {
    // fallback: f16 cell state if the workspace is small
    run_levels<_Float16>(x, c0, Wb, b_iou, U_f_b, out,
                         (_Float16*)(ws + wbBytes), stream);
  }
}

// Round 3
// 682.770 us; speedup vs baseline: 2.7603x; 1.0444x over previous
//
#include <hip/hip_runtime.h>
#include <math.h>

#define DEPTH 17
#define NNODES ((1 << DEPTH) - 1)

typedef _Float16 f16x8 __attribute__((ext_vector_type(8)));
typedef float f32x4 __attribute__((ext_vector_type(4)));

__device__ __forceinline__ float sigmoid_(float v) {
  return 1.0f / (1.0f + __expf(-v));
}
__device__ __forceinline__ float tanh_(float v) {
  float t = __expf(-2.0f * fabsf(v));
  float r = (1.0f - t) / (1.0f + t);
  return v < 0.0f ? -r : r;
}

// Pack combined weight matrix Wb[1280][768] f16, K contiguous per row:
//  rows 0..767   : [ W_iou (256) | U_iou (512) ]   -> iou outputs
//  rows 768..1279: [ 0     (256) | U_f_w (512) ]   -> f-gate outputs
__global__ __launch_bounds__(256) void build_wb(
    _Float16* __restrict__ Wb, const float* __restrict__ W_iou,
    const float* __restrict__ U_iou, const float* __restrict__ U_f_w) {
  int idx = blockIdx.x * 256 + threadIdx.x;  // grid covers exactly 1280*768
  int rw = idx / 768, k = idx - rw * 768;
  float v;
  if (rw < 768) {
    v = (k < 256) ? W_iou[rw * 256 + k] : U_iou[rw * 512 + (k - 256)];
  } else {
    v = (k < 256) ? 0.0f : U_f_w[(rw - 768) * 512 + (k - 256)];
  }
  Wb[idx] = (_Float16)v;
}

// One level: fused GEMM (A[m, K] @ Wb^T) + TreeLSTM node apply.
// Block tile: 64 rows x 64 n (x NG gate groups). 4 waves; wave w owns all
// 64 rows for n in [nb*64 + w*16, +16) across ALL groups -> wave-local
// epilogue. Pipelined reg-staging: chunk c+1's global loads are issued
// BEFORE chunk c's MFMA; the vmcnt drain at the post-compute barrier lands
// after ~400cyc of compute, hiding L2/HBM latency (T3 2-phase + T14).
// LDS single-buffered, K-chunk 64, kc^(row&7) XOR swizzle (conflict-free).
template <bool LEAF, bool H16, typename CT>
__global__ __launch_bounds__(256, 2) void level_kernel(
    const float* __restrict__ x, const float* __restrict__ c0in,
    const _Float16* __restrict__ Wb, const float* __restrict__ b_iou,
    const float* __restrict__ U_f_b, float* __restrict__ out,
    CT* __restrict__ cws, _Float16* __restrict__ hws, int m, int off,
    int coff) {
  constexpr int NG = LEAF ? 3 : 5;    // gate groups of 64 output cols
  constexpr int NCH = LEAF ? 4 : 12;  // K / 64
  constexpr int BROWS = NG * 64;
  constexpr int NBU = NG * 2;         // B f16x8 units per thread per chunk
  __shared__ f16x8 sA[64 * 8];        // 8 KB
  __shared__ f16x8 sB[BROWS * 8];     // 24 / 40 KB

  const int tid = threadIdx.x;
  const int w = tid >> 6;
  const int lane = tid & 63;
  const int l15 = lane & 15;
  const int q = lane >> 4;
  const int pbase = blockIdx.x << 6;
  const int nb = blockIdx.y;  // n-split index, 0..3

  const int arow = tid >> 3;  // staging row for unit 0 (unit j: +32*j)
  const int akc = tid & 7;    // staging k-chunk (16B unit within 64-k row)

  float4 ax[2][2];
  f16x8 ah[2];
  f16x8 bv[NBU];

  // ---- issue global loads for chunk c into registers
  auto LOAD = [&](int c) {
    const int k0 = (c << 6) + (akc << 3);
#pragma unroll
    for (int j = 0; j < 2; ++j) {
      const int row = arow + j * 32;
      const int p = pbase + row;
      const bool xpart = LEAF || c < 4;
      if (p < m) {
        if (xpart) {
          const float* src = x + (size_t)(off + p) * 256 + k0;
          ax[j][0] = *(const float4*)src;
          ax[j][1] = *(const float4*)(src + 4);
        } else if (H16) {
          ah[j] = *(const f16x8*)(hws + (size_t)(coff + 2 * p) * 256 +
                                  (k0 - 256));
        } else {
          const float* src = out + (size_t)(coff + 2 * p) * 256 + (k0 - 256);
          ax[j][0] = *(const float4*)src;
          ax[j][1] = *(const float4*)(src + 4);
        }
      } else {
        ax[j][0] = float4{0.f, 0.f, 0.f, 0.f};
        ax[j][1] = float4{0.f, 0.f, 0.f, 0.f};
        f16x8 z = {};
        ah[j] = z;
      }
    }
#pragma unroll
    for (int j = 0; j < NBU; ++j) {
      const int r = arow + j * 32;
      const int wbrow = (r >> 6) * 256 + nb * 64 + (r & 63);
      bv[j] = *(const f16x8*)(Wb + (size_t)wbrow * 768 + k0);
    }
  };

  // ---- convert (if needed) + ds_write staged regs to swizzled LDS slots
  auto WRITE = [&](int c) {
#pragma unroll
    for (int j = 0; j < 2; ++j) {
      const int row = arow + j * 32;
      f16x8 v;
      if (H16 && !LEAF && c >= 4) {
        v = ah[j];
      } else {
        v[0] = (_Float16)ax[j][0].x; v[1] = (_Float16)ax[j][0].y;
        v[2] = (_Float16)ax[j][0].z; v[3] = (_Float16)ax[j][0].w;
        v[4] = (_Float16)ax[j][1].x; v[5] = (_Float16)ax[j][1].y;
        v[6] = (_Float16)ax[j][1].z; v[7] = (_Float16)ax[j][1].w;
      }
      sA[(row << 3) | (akc ^ (row & 7))] = v;
    }
#pragma unroll
    for (int j = 0; j < NBU; ++j) {
      const int r = arow + j * 32;
      sB[(r << 3) | (akc ^ (r & 7))] = bv[j];
    }
  };

  f32x4 acc[NG][4] = {};

  LOAD(0);
  WRITE(0);
  __syncthreads();

  for (int c = 0; c < NCH; ++c) {
    if (c + 1 < NCH) LOAD(c + 1);  // in flight across the compute phase

    __builtin_amdgcn_s_setprio(1);
#pragma unroll
    for (int ks = 0; ks < 2; ++ks) {
      f16x8 af[4];
#pragma unroll
      for (int rf = 0; rf < 4; ++rf) {
        const int row = rf * 16 + l15;
        af[rf] = sA[(row << 3) | ((ks * 4 + q) ^ (row & 7))];
      }
#pragma unroll
      for (int g = 0; g < NG; ++g) {
        const int r = g * 64 + w * 16 + l15;
        const f16x8 bf = sB[(r << 3) | ((ks * 4 + q) ^ (r & 7))];
#pragma unroll
        for (int rf = 0; rf < 4; ++rf)
          acc[g][rf] = __builtin_amdgcn_mfma_f32_16x16x32_f16(
              af[rf], bf, acc[g][rf], 0, 0, 0);
      }
    }
    __builtin_amdgcn_s_setprio(0);
    __syncthreads();               // waves done reading (vmcnt drain lands here,
                                   // after compute -> latency hidden)
    if (c + 1 < NCH) {
      WRITE(c + 1);
      __syncthreads();             // writes visible before next compute
    }
  }

  // ---- epilogue: gates in f32, write h (d_out [+f16 ws]) and c (ws)
  const int n = nb * 64 + w * 16 + l15;  // n in [0,256)
  const float bi = b_iou[n];
  const float bo = b_iou[256 + n];
  const float bu = b_iou[512 + n];
  float bf0 = 0.f, bf1 = 0.f;
  if (!LEAF) { bf0 = U_f_b[n]; bf1 = U_f_b[256 + n]; }
#pragma unroll
  for (int rf = 0; rf < 4; ++rf) {
#pragma unroll
    for (int r = 0; r < 4; ++r) {
      const int p = pbase + rf * 16 + (q << 2) + r;
      if (p < m) {
        const float iv = sigmoid_(acc[0][rf][r] + bi);
        const float ov = sigmoid_(acc[1][rf][r] + bo);
        const float uv = tanh_(acc[2][rf][r] + bu);
        float cred;
        if (LEAF) {
          cred = c0in[(size_t)(off + p) * 256 + n];
        } else {
          const size_t cb = (size_t)(coff + 2 * p) * 256 + n;
          const float f0 = sigmoid_(acc[3][rf][r] + bf0);
          const float f1 = sigmoid_(acc[4][rf][r] + bf1);
          cred = f0 * (float)cws[cb] + f1 * (float)cws[cb + 256];
        }
        const float cc = iv * uv + cred;
        const float hh = ov * tanh_(cc);
        const size_t ob = (size_t)(off + p) * 256 + n;
        out[ob] = hh;
        cws[ob] = (CT)cc;
        if (H16) hws[ob] = (_Float16)hh;
      }
    }
  }
}

template <bool H16, typename CT>
static void run_levels(const float* x, const float* c0, const _Float16* Wb,
                       const float* b_iou, const float* U_f_b, float* out,
                       CT* cws, _Float16* hws, hipStream_t stream) {
  // leaves: level 16, m = 65536, off = 65535
  level_kernel<true, H16, CT><<<dim3(1024, 4), 256, 0, stream>>>(
      x, c0, Wb, b_iou, U_f_b, out, cws, hws, 65536, 65535, 0);
  for (int k = DEPTH - 2; k >= 0; --k) {
    const int m = 1 << k;
    level_kernel<false, H16, CT><<<dim3((m + 63) / 64, 4), 256, 0, stream>>>(
        x, c0, Wb, b_iou, U_f_b, out, cws, hws, m, m - 1, 2 * m - 1);
  }
}

extern "C" void kernel_launch(void* const* d_in, const int* in_sizes, int n_in,
                              void* d_out, int out_size, void* d_ws, size_t ws_size,
                              hipStream_t stream) {
  const float* x     = (const float*)d_in[0];
  // d_in[1] = h0 (unused by the reference's math)
  const float* c0    = (const float*)d_in[2];
  const float* W_iou = (const float*)d_in[3];
  const float* U_iou = (const float*)d_in[4];
  const float* b_iou = (const float*)d_in[5];
  const float* U_f_w = (const float*)d_in[6];
  const float* U_f_b = (const float*)d_in[7];
  float* out = (float*)d_out;

  char* ws = (char*)d_ws;
  const size_t wbBytes = (size_t)1280 * 768 * 2;  // 1.97 MB, 16B-aligned
  _Float16* Wb = (_Float16*)ws;
  build_wb<<<3840, 256, 0, stream>>>(Wb, W_iou, U_iou, U_f_w);

  const size_t cElems = (size_t)NNODES * 256;
  char* p1 = ws + wbBytes;
  if (ws_size >= wbBytes + cElems * 4 + cElems * 2) {
    // c in f32, h mirrored in f16 (identical numerics to the MFMA staging)
    run_levels<true, float>(x, c0, Wb, b_iou, U_f_b, out, (float*)p1,
                            (_Float16*)(p1 + cElems * 4), stream);
  } else if (ws_size >= wbBytes + cElems * 4) {
    run_levels<false, float>(x, c0, Wb, b_iou, U_f_b, out, (float*)p1,
                             nullptr, stream);
  } else {
    run_levels<false, _Float16>(x, c0, Wb, b_iou, U_f_b, out, (_Float16*)p1,
                                nullptr, stream);
  }
}